// Round 3
// baseline (397.965 us; speedup 1.0000x reference)
//
#include <hip/hip_runtime.h>
#include <hip/hip_bf16.h>

// PSWarpHead round 9. conv1: double-buffered chunk staging + XCD swizzle.
//   transpose: fp32 x [b][c][hw] -> bf16 xT [b][hw][c]   (unchanged, validated)
//   conv1: per (b,y) block, 8 chunks of 32 channels, 2-phase pipeline:
//          prologue stages chunk0 -> buf0; iter j stages chunk j+1 -> buf[j+1&1]
//          (6-wave split staging), computes chunk j from buf[j&1], ONE barrier
//          per chunk. XCD-chunked block swizzle (800%8==0 -> bijective) gives
//          each XCD a contiguous 100-row strip for halo/L2-line reuse.
//          Epilogue t2 tile ALIASED over buf0 (dead after last barrier).
//   sample: 4-corner scalar gather of feat2 (unchanged from r7/r8)
// LDS: 2 x 3*178*32 bf16 = 68,352 B -> 2 blocks/CU.
// Accumulation order identical to r8 -> same numerics (absmax ~1e-3).

#define WDIM 176
#define HDIM 200
#define HWDIM 35200
#define CIN 256
#define PDIM 28
#define NBOX 2048

#define AS_ELEMS (3 * 178 * 32)   // 17088 elems (34,176 B) per buffer
#define ROW_STRIDE (178 * 32)     // 5696 elems per staged row

typedef __attribute__((ext_vector_type(8))) short bf16x8;
typedef __attribute__((ext_vector_type(4))) float floatx4;

__device__ __forceinline__ unsigned short f2bf(float f) {
    unsigned int u; __builtin_memcpy(&u, &f, 4);
    unsigned int r = u + 0x7FFFu + ((u >> 16) & 1u);   // RNE
    return (unsigned short)(r >> 16);
}

__device__ __forceinline__ void async_copy16(const void* g, void* l) {
    __builtin_amdgcn_global_load_lds(
        (const __attribute__((address_space(1))) void*)g,
        (__attribute__((address_space(3))) void*)l, 16, 0, 0);
}

// ---------- transpose: fp32 x [b][c][hw] -> bf16 xT [b][hw][c] ----------
__global__ __launch_bounds__(256) void transpose_kernel(const float* __restrict__ x,
                                                        unsigned short* __restrict__ xT) {
    __shared__ unsigned short tile[32][80];
    int b = blockIdx.z, c0 = blockIdx.y * 32, px0 = blockIdx.x * 64;
    int t = threadIdx.x;
    int c_l = t >> 3, pxg = (t & 7) * 8;
    const float* sp = x + (long)(b * CIN + c0 + c_l) * HWDIM + px0 + pxg;
    float4 a = ((const float4*)sp)[0], bq = ((const float4*)sp)[1];
    tile[c_l][pxg + 0] = f2bf(a.x);  tile[c_l][pxg + 1] = f2bf(a.y);
    tile[c_l][pxg + 2] = f2bf(a.z);  tile[c_l][pxg + 3] = f2bf(a.w);
    tile[c_l][pxg + 4] = f2bf(bq.x); tile[c_l][pxg + 5] = f2bf(bq.y);
    tile[c_l][pxg + 6] = f2bf(bq.z); tile[c_l][pxg + 7] = f2bf(bq.w);
    __syncthreads();
    int px_l = t >> 2, cg = (t & 3) * 8;
    ushort4 o0, o1;
    o0.x = tile[cg + 0][px_l]; o0.y = tile[cg + 1][px_l];
    o0.z = tile[cg + 2][px_l]; o0.w = tile[cg + 3][px_l];
    o1.x = tile[cg + 4][px_l]; o1.y = tile[cg + 5][px_l];
    o1.z = tile[cg + 6][px_l]; o1.w = tile[cg + 7][px_l];
    long dst = (long)(b * HWDIM + px0 + px_l) * CIN + c0 + cg;
    *(ushort4*)(xT + dst) = o0;
    *(ushort4*)(xT + dst + 4) = o1;
}

// ---------- prep: BwT[tap][n(32,pad0)][c] bf16; BN fold (fp32 in) ----------
__global__ void prep_kernel(const float* __restrict__ w1,
                            const float* __restrict__ g, const float* __restrict__ bt,
                            const float* __restrict__ mn, const float* __restrict__ vr,
                            unsigned short* __restrict__ BwT,
                            float* __restrict__ scale, float* __restrict__ shift) {
    int idx = blockIdx.x * 256 + threadIdx.x;
    if (idx < 9 * 32 * 256) {
        int tap = idx >> 13;
        int r = idx & 8191;
        int n = r >> 8, c = r & 255;
        BwT[idx] = (n < PDIM) ? f2bf(w1[n * 2304 + c * 9 + tap]) : (unsigned short)0;
    } else if (idx < 73728 + 32) {
        int p = idx - 73728;
        if (p < PDIM) {
            float inv = g[p] / sqrtf(vr[p] + 1e-3f);
            scale[p] = inv;
            shift[p] = bt[p] - mn[p] * inv;
        } else { scale[p] = 0.f; shift[p] = 0.f; }
    }
}

// ---------- conv1 (double-buffered LDS-staged MFMA) + fused epilogue ----------
// block = (b,y) row: 6 waves, wave w -> px [w*32, w*32+32) (wave 5: 16 px).
__global__ __launch_bounds__(384) void conv1_kernel(const unsigned short* __restrict__ xT,
                                                    const unsigned short* __restrict__ BwT,
                                                    const float* __restrict__ scale,
                                                    const float* __restrict__ shift,
                                                    const float* __restrict__ w2,
                                                    float* __restrict__ feat2) {
    // two A-stage buffers: [buf][row 0..2][px-slot 0..177][c 0..31] bf16.
    // slots 0/177 are never-written halo (reads masked). t2 epilogue tile
    // (13,824 B) aliases buf0 (dead after the final loop barrier).
    __shared__ unsigned short sh[2 * AS_ELEMS];

    // XCD-chunked bijective swizzle: 800 blocks, XCD k owns nl in [k*100,k*100+100)
    int wg = blockIdx.x + HDIM * blockIdx.y;          // 0..799, dispatch order
    int nl = (wg & 7) * 100 + (wg >> 3);              // bijective (800 % 8 == 0)
    int y = nl % HDIM, b = nl / HDIM;

    int lane = threadIdx.x & 63, w = threadIdx.x >> 6;
    int nmt = (w == 5) ? 1 : 2;
    int lm = lane & 15, kg = lane >> 4;
    int kg8 = kg * 8;
    int pxb = w * 32;

    bool rowok[3];
#pragma unroll
    for (int rr = 0; rr < 3; rr++) rowok[rr] = (y + rr - 1 >= 0) && (y + rr - 1 < HDIM);

    // per-(mt,d) LDS element offset of this lane's A fragment + validity
    int  aoff[2][3];
    bool xval[2][3];
#pragma unroll
    for (int mt = 0; mt < 2; mt++) {
#pragma unroll
        for (int d = 0; d < 3; d++) {
            int xp = pxb + mt * 16 + lm + (d - 1);        // -1 .. 176
            xval[mt][d] = (xp >= 0) && (xp < WDIM);
            aoff[mt][d] = (1 + xp) * 32 + kg8;            // slot px+1 in [0,178)
        }
    }

    // 6-wave staging split: wave w stages half-row (rr = w>>1, half = w&1).
    // half 0: px 0..95 (6 loads), half 1: px 96..175 (5 loads).
    int rr_s = w >> 1;
    int i0 = (w & 1) * 6;
    int ni = (w & 1) ? 5 : 6;
    const unsigned short* gsrc0 = nullptr;
    int ldst0 = 0;
    if (rowok[rr_s]) {
        gsrc0 = xT + ((long)(b * HDIM + y + rr_s - 1) * WDIM + i0 * 16 + (lane >> 2)) * CIN
                   + (lane & 3) * 8;
        ldst0 = rr_s * ROW_STRIDE + (1 + i0 * 16) * 32;
    }

    // prologue: stage chunk 0 -> buf0
    if (gsrc0) {
#pragma unroll
        for (int i = 0; i < 6; i++)
            if (i < ni) async_copy16(gsrc0 + (long)i * 16 * CIN, &sh[ldst0 + i * 512]);
    }
    __syncthreads();

    floatx4 acc[2][2] = {{{0.f,0.f,0.f,0.f},{0.f,0.f,0.f,0.f}},
                         {{0.f,0.f,0.f,0.f},{0.f,0.f,0.f,0.f}}};

    for (int j = 0; j < 8; j++) {
        int cofs = j * 32 + kg8;
        // B fragments for this chunk (L2-hot, issued before the stage so the
        // compiler's counted vmcnt for bfr does not drain the stage loads)
        bf16x8 bfr[9][2];
#pragma unroll
        for (int tap = 0; tap < 9; tap++) {
            const unsigned short* bp = BwT + ((tap * 32 + lm) << 8) + cofs;
            bfr[tap][0] = *(const bf16x8*)bp;
            bfr[tap][1] = *(const bf16x8*)(bp + 4096);   // n-tile 1
        }

        // stage chunk j+1 into the other buffer (overlaps with compute below)
        if (j < 7 && gsrc0) {
            int nb = ((j + 1) & 1) * AS_ELEMS;
            const unsigned short* gs = gsrc0 + (j + 1) * 32;
#pragma unroll
            for (int i = 0; i < 6; i++)
                if (i < ni) async_copy16(gs + (long)i * 16 * CIN, &sh[nb + ldst0 + i * 512]);
        }

        // compute chunk j from buf[j&1]
        const unsigned short* cur = &sh[(j & 1) * AS_ELEMS];
#pragma unroll
        for (int tap = 0; tap < 9; tap++) {
            int rr = tap / 3, d = tap % 3;
            if (!rowok[rr]) continue;          // block-uniform
            const unsigned short* rbase = cur + rr * ROW_STRIDE;
#pragma unroll
            for (int mt = 0; mt < 2; mt++) {
                if (mt < nmt) {
                    bf16x8 afr = *(const bf16x8*)&rbase[aoff[mt][d]];
                    if (!xval[mt][d]) afr = (bf16x8)0;
                    acc[mt][0] = __builtin_amdgcn_mfma_f32_16x16x32_bf16(afr, bfr[tap][0], acc[mt][0], 0, 0, 0);
                    acc[mt][1] = __builtin_amdgcn_mfma_f32_16x16x32_bf16(afr, bfr[tap][1], acc[mt][1], 0, 0, 0);
                }
            }
        }
        __syncthreads();   // buf[j&1] free for the j+1 iteration's stage
    }

    // ---- epilogue: BN + relu -> per-wave LDS tile (aliased over buf0) ----
    // acc C/D layout: col n = lane&15 (+nt*16), row pxl = (lane>>4)*4 + r.
    float* t2f = (float*)sh;                  // [6][16][36] fp32, 13,824 B
#define T2(W, R, N) t2f[((W) * 16 + (R)) * 36 + (N)]
    long rowpix = (long)b * HWDIM + (long)y * WDIM;
    int n_l = lane & 31;           // output channel handled by this lane (<28 valid)
    int half = lane >> 5;          // lanes 0-31 do px 0-7, lanes 32-63 do px 8-15
    float4 w2r[7];
#pragma unroll
    for (int jj = 0; jj < 7; jj++) {
        if (n_l < PDIM) w2r[jj] = ((const float4*)(w2 + n_l * PDIM))[jj];
        else            w2r[jj] = make_float4(0.f, 0.f, 0.f, 0.f);
    }

#pragma unroll
    for (int mt = 0; mt < 2; mt++) {
        if (mt < nmt) {
#pragma unroll
            for (int nt = 0; nt < 2; nt++) {
                int n = nt * 16 + lm;
                float sc = scale[n], sh2 = shift[n];
#pragma unroll
                for (int r = 0; r < 4; r++) {
                    float v = fmaf(acc[mt][nt][r], sc, sh2);
                    T2(w, kg * 4 + r, n) = v > 0.f ? v : 0.f;
                }
            }
            // intra-wave LDS dependency: compiler inserts lgkmcnt waits.
#pragma unroll
            for (int i = 0; i < 8; i++) {
                int pxl = half * 8 + i;
                float s = 0.f;
#pragma unroll
                for (int jj = 0; jj < 7; jj++) {
                    float4 a = *(const float4*)&T2(w, pxl, jj * 4);
                    s = fmaf(a.x, w2r[jj].x, s); s = fmaf(a.y, w2r[jj].y, s);
                    s = fmaf(a.z, w2r[jj].z, s); s = fmaf(a.w, w2r[jj].w, s);
                }
                int px = pxb + mt * 16 + pxl;
                if (n_l < PDIM) feat2[(rowpix + px) * PDIM + n_l] = s;
            }
        }
    }
#undef T2
}

// ---------- PS bilinear sampler on precomputed conv2 output (scalar gather) ----------
__global__ __launch_bounds__(256) void sample_kernel(const float* __restrict__ boxes,
                                                     const float* __restrict__ feat2,
                                                     float* __restrict__ out) {
    int gid = blockIdx.x * 256 + threadIdx.x;
    int box = gid >> 5;              // 32 lanes per box
    int pl = gid & 31;
    int b = box >> 11;
    float val = 0.f;
    if (pl < PDIM) {
        long bb = (long)box * 7;
        float xg = boxes[bb + 0], yg = boxes[bb + 1];
        float wg = boxes[bb + 3], lg = boxes[bb + 4];
        float rg = boxes[bb + 6];
        float ct = cosf(rg), st = sinf(rg);
        const float lxv[4] = {-0.5f, -0.16666667f, 0.16666667f, 0.5f};
        const float lyv[7] = {-0.5f, -0.33333334f, -0.16666667f, 0.f,
                               0.16666667f, 0.33333334f, 0.5f};
        int h = pl / 7, ww = pl - (pl / 7) * 7;
        float xx = lxv[h] * wg;
        float yy = lyv[ww] * lg;
        float gx = (xx * ct + yy * st + xg) * 2.5f;           // GRID_OFF.x = 0
        float gy = (yy * ct - xx * st + yg + 40.f) * 2.5f;    // GRID_OFF.y = 40
        float x0 = floorf(gx), y0 = floorf(gy);
        float fx = gx - x0, fy = gy - y0;
        int xi = (int)x0, yi = (int)y0;
        const float* base = feat2 + (long)b * HWDIM * PDIM + pl;
        float Ia = 0.f, Ib = 0.f, Ic = 0.f, Id = 0.f;
        if (yi >= 0 && yi < HDIM) {
            long r0 = (long)yi * WDIM;
            if (xi >= 0 && xi < WDIM)         Ia = base[(r0 + xi) * PDIM];
            if (xi + 1 >= 0 && xi + 1 < WDIM) Ic = base[(r0 + xi + 1) * PDIM];
        }
        if (yi + 1 >= 0 && yi + 1 < HDIM) {
            long r1 = (long)(yi + 1) * WDIM;
            if (xi >= 0 && xi < WDIM)         Ib = base[(r1 + xi) * PDIM];
            if (xi + 1 >= 0 && xi + 1 < WDIM) Id = base[(r1 + xi + 1) * PDIM];
        }
        val = (1.f - fx) * (1.f - fy) * Ia + (1.f - fx) * fy * Ib
            + fx * (1.f - fy) * Ic + fx * fy * Id;
    }
#pragma unroll
    for (int m = 16; m >= 1; m >>= 1) val += __shfl_xor(val, m, 64);
    if ((threadIdx.x & 31) == 0) {
        out[box] = val * (1.f / 28.f);
    }
}

// ---------- launch ----------
extern "C" void kernel_launch(void* const* d_in, const int* in_sizes, int n_in,
                              void* d_out, int out_size, void* d_ws, size_t ws_size,
                              hipStream_t stream) {
    const float* x     = (const float*)d_in[0];
    const float* boxes = (const float*)d_in[1];
    const float* w1    = (const float*)d_in[2];
    const float* g     = (const float*)d_in[3];
    const float* bt    = (const float*)d_in[4];
    const float* mn    = (const float*)d_in[5];
    const float* vr    = (const float*)d_in[6];
    const float* w2    = (const float*)d_in[7];
    float* out = (float*)d_out;

    char* ws = (char*)d_ws;
    unsigned short* xT  = (unsigned short*)ws;                 // 72,089,600 B
    float* feat2        = (float*)(ws + 72089600);             // 15,769,600 B
    unsigned short* BwT = (unsigned short*)(ws + 90112000);    //    147,456 B
    float* scale        = (float*)(ws + 90259456);             //        128 B
    float* shift        = (float*)(ws + 90259584);             //        128 B

    transpose_kernel<<<dim3(550, 8, 4), 256, 0, stream>>>(x, xT);
    prep_kernel<<<289, 256, 0, stream>>>(w1, g, bt, mn, vr, BwT, scale, shift);
    conv1_kernel<<<dim3(HDIM, 4), 384, 0, stream>>>(xT, BwT, scale, shift, w2, feat2);
    sample_kernel<<<1024, 256, 0, stream>>>(boxes, feat2, out);
}

// Round 4
// 350.294 us; speedup vs baseline: 1.1361x; 1.1361x over previous
//
#include <hip/hip_runtime.h>
#include <hip/hip_bf16.h>

// PSWarpHead round 10. conv1: occupancy restructure.
//   r9 post-mortem: FETCH 139->36MB (swizzle works) but time flat -> latency
//   bound with only ~4.3 waves/CU avg. Fix: half-row blocks (96/80 px), 3
//   waves (192 thr), single-buffer LDS 25.7KB -> 6 blocks/CU (18 waves/CU),
//   1600 blocks. One stage-row per wave. bfr loads issued pre-barrier.
//   transpose / prep / sample unchanged (r7/r8-validated).
// Accumulation order identical -> same numerics (absmax ~1e-3).

#define WDIM 176
#define HDIM 200
#define HWDIM 35200
#define CIN 256
#define PDIM 28
#define NBOX 2048

#define ROW_SLOTS 98              // px-slots per staged row (slot = xp - pxbase + 1)
#define AS_ROW (ROW_SLOTS * 32)   // 3136 elems per row
#define AS_ELEMS (3 * AS_ROW)     // 9408 elems = 18,816 B

typedef __attribute__((ext_vector_type(8))) short bf16x8;
typedef __attribute__((ext_vector_type(4))) float floatx4;

__device__ __forceinline__ unsigned short f2bf(float f) {
    unsigned int u; __builtin_memcpy(&u, &f, 4);
    unsigned int r = u + 0x7FFFu + ((u >> 16) & 1u);   // RNE
    return (unsigned short)(r >> 16);
}

__device__ __forceinline__ void async_copy16(const void* g, void* l) {
    __builtin_amdgcn_global_load_lds(
        (const __attribute__((address_space(1))) void*)g,
        (__attribute__((address_space(3))) void*)l, 16, 0, 0);
}

// ---------- transpose: fp32 x [b][c][hw] -> bf16 xT [b][hw][c] ----------
__global__ __launch_bounds__(256) void transpose_kernel(const float* __restrict__ x,
                                                        unsigned short* __restrict__ xT) {
    __shared__ unsigned short tile[32][80];
    int b = blockIdx.z, c0 = blockIdx.y * 32, px0 = blockIdx.x * 64;
    int t = threadIdx.x;
    int c_l = t >> 3, pxg = (t & 7) * 8;
    const float* sp = x + (long)(b * CIN + c0 + c_l) * HWDIM + px0 + pxg;
    float4 a = ((const float4*)sp)[0], bq = ((const float4*)sp)[1];
    tile[c_l][pxg + 0] = f2bf(a.x);  tile[c_l][pxg + 1] = f2bf(a.y);
    tile[c_l][pxg + 2] = f2bf(a.z);  tile[c_l][pxg + 3] = f2bf(a.w);
    tile[c_l][pxg + 4] = f2bf(bq.x); tile[c_l][pxg + 5] = f2bf(bq.y);
    tile[c_l][pxg + 6] = f2bf(bq.z); tile[c_l][pxg + 7] = f2bf(bq.w);
    __syncthreads();
    int px_l = t >> 2, cg = (t & 3) * 8;
    ushort4 o0, o1;
    o0.x = tile[cg + 0][px_l]; o0.y = tile[cg + 1][px_l];
    o0.z = tile[cg + 2][px_l]; o0.w = tile[cg + 3][px_l];
    o1.x = tile[cg + 4][px_l]; o1.y = tile[cg + 5][px_l];
    o1.z = tile[cg + 6][px_l]; o1.w = tile[cg + 7][px_l];
    long dst = (long)(b * HWDIM + px0 + px_l) * CIN + c0 + cg;
    *(ushort4*)(xT + dst) = o0;
    *(ushort4*)(xT + dst + 4) = o1;
}

// ---------- prep: BwT[tap][n(32,pad0)][c] bf16; BN fold (fp32 in) ----------
__global__ void prep_kernel(const float* __restrict__ w1,
                            const float* __restrict__ g, const float* __restrict__ bt,
                            const float* __restrict__ mn, const float* __restrict__ vr,
                            unsigned short* __restrict__ BwT,
                            float* __restrict__ scale, float* __restrict__ shift) {
    int idx = blockIdx.x * 256 + threadIdx.x;
    if (idx < 9 * 32 * 256) {
        int tap = idx >> 13;
        int r = idx & 8191;
        int n = r >> 8, c = r & 255;
        BwT[idx] = (n < PDIM) ? f2bf(w1[n * 2304 + c * 9 + tap]) : (unsigned short)0;
    } else if (idx < 73728 + 32) {
        int p = idx - 73728;
        if (p < PDIM) {
            float inv = g[p] / sqrtf(vr[p] + 1e-3f);
            scale[p] = inv;
            shift[p] = bt[p] - mn[p] * inv;
        } else { scale[p] = 0.f; shift[p] = 0.f; }
    }
}

// ---------- conv1 (LDS-staged MFMA, half-row blocks) + fused epilogue ----------
// block = (b, y, half): half 0 -> px 0..95 (6 tiles), half 1 -> px 96..175
// (5 tiles). 3 waves; wave w owns tiles 2w,2w+1 and stages input row w.
__global__ __launch_bounds__(192) void conv1_kernel(const unsigned short* __restrict__ xT,
                                                    const unsigned short* __restrict__ BwT,
                                                    const float* __restrict__ scale,
                                                    const float* __restrict__ shift,
                                                    const float* __restrict__ w2,
                                                    float* __restrict__ feat2) {
    // As[row 0..2][slot 0..97][c 0..31]; slot = xp - pxbase + 1. Slots that
    // map to xp outside [0,176) are never written; reads of them are masked.
    __shared__ unsigned short As[AS_ELEMS];
    __shared__ float t2f[3 * 16 * 36];        // per-wave epilogue tile

    // XCD-chunked bijective swizzle over 1600 blocks (1600 % 8 == 0):
    // XCD k owns nl in [k*200, k*200+200) -> contiguous (b,y,half) strip.
    int wg = blockIdx.y * 400 + blockIdx.x;
    int nl = (wg & 7) * 200 + (wg >> 3);
    int b = nl / 400;
    int r = nl - b * 400;
    int y = r >> 1, half = r & 1;
    int pxbase = half * 96;
    int tiles_total = half ? 5 : 6;

    int lane = threadIdx.x & 63, w = threadIdx.x >> 6;    // w in 0..2
    int lm = lane & 15, kg = lane >> 4, kg8 = kg * 8;
    int nmt = tiles_total - 2 * w; if (nmt > 2) nmt = 2;  // 2,2,2 / 2,2,1

    bool rowok[3];
#pragma unroll
    for (int rr = 0; rr < 3; rr++) rowok[rr] = (y + rr - 1 >= 0) && (y + rr - 1 < HDIM);

    // per-(mt,d) LDS element offset of this lane's A fragment + validity
    int  aoff[2][3];
    bool xval[2][3];
#pragma unroll
    for (int mt = 0; mt < 2; mt++) {
#pragma unroll
        for (int d = 0; d < 3; d++) {
            int tile = 2 * w + mt;
            int xp = pxbase + tile * 16 + lm + (d - 1);
            xval[mt][d] = (xp >= 0) && (xp < WDIM);
            aoff[mt][d] = (tile * 16 + lm + d) * 32 + kg8;  // slot*32 + kg8
        }
    }

    // staging: wave w stages input row y+w-1 of its px window.
    // half0: 7 loads, p0 = 0,16,32,48,64,80,81 -> slots p0+1  (covers xp 0..96)
    // half1: 6 loads, p0 = 95,111,127,143,159,160 -> slots p0-95 (covers xp 95..175)
    // overlapping loads rewrite identical bytes (same global px) - benign.
    const unsigned short* gRow = xT
        + ((long)(b * HDIM + (y + w - 1)) * WDIM + (lane >> 2)) * CIN + (lane & 3) * 8;
    unsigned short* lRow = As + w * AS_ROW;
    bool doStage = rowok[w];

    floatx4 acc[2][2] = {{{0.f,0.f,0.f,0.f},{0.f,0.f,0.f,0.f}},
                         {{0.f,0.f,0.f,0.f},{0.f,0.f,0.f,0.f}}};

    for (int j = 0; j < 8; j++) {
        if (j) __syncthreads();                 // As free (all waves done reading)
        if (doStage) {
            const unsigned short* gs = gRow + j * 32;
            if (half == 0) {
                async_copy16(gs +  0L * CIN, lRow +  1 * 32);
                async_copy16(gs + 16L * CIN, lRow + 17 * 32);
                async_copy16(gs + 32L * CIN, lRow + 33 * 32);
                async_copy16(gs + 48L * CIN, lRow + 49 * 32);
                async_copy16(gs + 64L * CIN, lRow + 65 * 32);
                async_copy16(gs + 80L * CIN, lRow + 81 * 32);
                async_copy16(gs + 81L * CIN, lRow + 82 * 32);
            } else {
                async_copy16(gs +  95L * CIN, lRow +  0 * 32);
                async_copy16(gs + 111L * CIN, lRow + 16 * 32);
                async_copy16(gs + 127L * CIN, lRow + 32 * 32);
                async_copy16(gs + 143L * CIN, lRow + 48 * 32);
                async_copy16(gs + 159L * CIN, lRow + 64 * 32);
                async_copy16(gs + 160L * CIN, lRow + 65 * 32);
            }
        }
        // B fragments (L2-hot, independent of As) issued before the barrier so
        // their latency overlaps the stage drain.
        int cofs = j * 32 + kg8;
        bf16x8 bfr[9][2];
#pragma unroll
        for (int tap = 0; tap < 9; tap++) {
            const unsigned short* bp = BwT + ((tap * 32 + lm) << 8) + cofs;
            bfr[tap][0] = *(const bf16x8*)bp;
            bfr[tap][1] = *(const bf16x8*)(bp + 4096);   // n-tile 1
        }
        __syncthreads();                        // stage visible (vmcnt drained)

#pragma unroll
        for (int tap = 0; tap < 9; tap++) {
            int rr = tap / 3, d = tap % 3;
            if (!rowok[rr]) continue;           // block-uniform
            const unsigned short* rbase = As + rr * AS_ROW;
#pragma unroll
            for (int mt = 0; mt < 2; mt++) {
                if (mt < nmt) {
                    bf16x8 afr = *(const bf16x8*)&rbase[aoff[mt][d]];
                    if (!xval[mt][d]) afr = (bf16x8)0;
                    acc[mt][0] = __builtin_amdgcn_mfma_f32_16x16x32_bf16(afr, bfr[tap][0], acc[mt][0], 0, 0, 0);
                    acc[mt][1] = __builtin_amdgcn_mfma_f32_16x16x32_bf16(afr, bfr[tap][1], acc[mt][1], 0, 0, 0);
                }
            }
        }
    }

    // ---- epilogue: BN + relu -> per-wave LDS tile -> fp32 conv2 matvec ----
    // acc C/D layout: col n = lane&15 (+nt*16), row pxl = (lane>>4)*4 + r.
#define T2(W, R, N) t2f[((W) * 16 + (R)) * 36 + (N)]
    long rowpix = (long)b * HWDIM + (long)y * WDIM;
    int n_l = lane & 31;           // output channel handled by this lane (<28 valid)
    int hlf = lane >> 5;           // lanes 0-31 do px 0-7, lanes 32-63 do px 8-15
    float4 w2r[7];
#pragma unroll
    for (int jj = 0; jj < 7; jj++) {
        if (n_l < PDIM) w2r[jj] = ((const float4*)(w2 + n_l * PDIM))[jj];
        else            w2r[jj] = make_float4(0.f, 0.f, 0.f, 0.f);
    }

#pragma unroll
    for (int mt = 0; mt < 2; mt++) {
        if (mt < nmt) {
#pragma unroll
            for (int nt = 0; nt < 2; nt++) {
                int n = nt * 16 + lm;
                float sc = scale[n], sh2 = shift[n];
#pragma unroll
                for (int rg = 0; rg < 4; rg++) {
                    float v = fmaf(acc[mt][nt][rg], sc, sh2);
                    T2(w, kg * 4 + rg, n) = v > 0.f ? v : 0.f;
                }
            }
            // intra-wave LDS dependency: compiler inserts lgkmcnt waits.
#pragma unroll
            for (int i = 0; i < 8; i++) {
                int pxl = hlf * 8 + i;
                float s = 0.f;
#pragma unroll
                for (int jj = 0; jj < 7; jj++) {
                    float4 a = *(const float4*)&T2(w, pxl, jj * 4);
                    s = fmaf(a.x, w2r[jj].x, s); s = fmaf(a.y, w2r[jj].y, s);
                    s = fmaf(a.z, w2r[jj].z, s); s = fmaf(a.w, w2r[jj].w, s);
                }
                int px = pxbase + (2 * w + mt) * 16 + pxl;
                if (n_l < PDIM) feat2[(rowpix + px) * PDIM + n_l] = s;
            }
        }
    }
#undef T2
}

// ---------- PS bilinear sampler on precomputed conv2 output (scalar gather) ----------
__global__ __launch_bounds__(256) void sample_kernel(const float* __restrict__ boxes,
                                                     const float* __restrict__ feat2,
                                                     float* __restrict__ out) {
    int gid = blockIdx.x * 256 + threadIdx.x;
    int box = gid >> 5;              // 32 lanes per box
    int pl = gid & 31;
    int b = box >> 11;
    float val = 0.f;
    if (pl < PDIM) {
        long bb = (long)box * 7;
        float xg = boxes[bb + 0], yg = boxes[bb + 1];
        float wg = boxes[bb + 3], lg = boxes[bb + 4];
        float rg = boxes[bb + 6];
        float ct = cosf(rg), st = sinf(rg);
        const float lxv[4] = {-0.5f, -0.16666667f, 0.16666667f, 0.5f};
        const float lyv[7] = {-0.5f, -0.33333334f, -0.16666667f, 0.f,
                               0.16666667f, 0.33333334f, 0.5f};
        int h = pl / 7, ww = pl - (pl / 7) * 7;
        float xx = lxv[h] * wg;
        float yy = lyv[ww] * lg;
        float gx = (xx * ct + yy * st + xg) * 2.5f;           // GRID_OFF.x = 0
        float gy = (yy * ct - xx * st + yg + 40.f) * 2.5f;    // GRID_OFF.y = 40
        float x0 = floorf(gx), y0 = floorf(gy);
        float fx = gx - x0, fy = gy - y0;
        int xi = (int)x0, yi = (int)y0;
        const float* base = feat2 + (long)b * HWDIM * PDIM + pl;
        float Ia = 0.f, Ib = 0.f, Ic = 0.f, Id = 0.f;
        if (yi >= 0 && yi < HDIM) {
            long r0 = (long)yi * WDIM;
            if (xi >= 0 && xi < WDIM)         Ia = base[(r0 + xi) * PDIM];
            if (xi + 1 >= 0 && xi + 1 < WDIM) Ic = base[(r0 + xi + 1) * PDIM];
        }
        if (yi + 1 >= 0 && yi + 1 < HDIM) {
            long r1 = (long)(yi + 1) * WDIM;
            if (xi >= 0 && xi < WDIM)         Ib = base[(r1 + xi) * PDIM];
            if (xi + 1 >= 0 && xi + 1 < WDIM) Id = base[(r1 + xi + 1) * PDIM];
        }
        val = (1.f - fx) * (1.f - fy) * Ia + (1.f - fx) * fy * Ib
            + fx * (1.f - fy) * Ic + fx * fy * Id;
    }
#pragma unroll
    for (int m = 16; m >= 1; m >>= 1) val += __shfl_xor(val, m, 64);
    if ((threadIdx.x & 31) == 0) {
        out[box] = val * (1.f / 28.f);
    }
}

// ---------- launch ----------
extern "C" void kernel_launch(void* const* d_in, const int* in_sizes, int n_in,
                              void* d_out, int out_size, void* d_ws, size_t ws_size,
                              hipStream_t stream) {
    const float* x     = (const float*)d_in[0];
    const float* boxes = (const float*)d_in[1];
    const float* w1    = (const float*)d_in[2];
    const float* g     = (const float*)d_in[3];
    const float* bt    = (const float*)d_in[4];
    const float* mn    = (const float*)d_in[5];
    const float* vr    = (const float*)d_in[6];
    const float* w2    = (const float*)d_in[7];
    float* out = (float*)d_out;

    char* ws = (char*)d_ws;
    unsigned short* xT  = (unsigned short*)ws;                 // 72,089,600 B
    float* feat2        = (float*)(ws + 72089600);             // 15,769,600 B
    unsigned short* BwT = (unsigned short*)(ws + 90112000);    //    147,456 B
    float* scale        = (float*)(ws + 90259456);             //        128 B
    float* shift        = (float*)(ws + 90259584);             //        128 B

    transpose_kernel<<<dim3(550, 8, 4), 256, 0, stream>>>(x, xT);
    prep_kernel<<<289, 256, 0, stream>>>(w1, g, bt, mn, vr, BwT, scale, shift);
    conv1_kernel<<<dim3(400, 4), 192, 0, stream>>>(xT, BwT, scale, shift, w2, feat2);
    sample_kernel<<<1024, 256, 0, stream>>>(boxes, feat2, out);
}

// Round 5
// 342.374 us; speedup vs baseline: 1.1624x; 1.0231x over previous
//
#include <hip/hip_runtime.h>
#include <hip/hip_bf16.h>

// PSWarpHead round 11. conv1: barrier-free wave-private pipeline.
//   r10 post-mortem: occupancy 31% helped (159->114us) but both pipes still
//   <14% busy -> 3-wave barrier convoy (2 syncthreads/chunk, each a vmcnt(0)
//   drain) re-exposes stage latency 16x/block. Fix: 1-wave blocks (64 thr),
//   wave-private dbuf staging (34-slot window, 13KB LDS -> 12 blocks/CU),
//   ZERO barriers, hand-counted vmcnt (T4): per chunk issue 18 bfr + 9 stage
//   loads then s_waitcnt vmcnt(27) -- chunk j+1's DMA stays in flight through
//   chunk j's MFMAs. Stage is always 9 loads (y-clamped, rows masked on read)
//   so waitcnt constants are exact. 4800 blocks, bijective XCD swizzle.
//   transpose / prep / sample unchanged (r7-r10 validated).
// Accumulation order identical -> same numerics (absmax ~1e-3).

#define WDIM 176
#define HDIM 200
#define HWDIM 35200
#define CIN 256
#define PDIM 28
#define NBOX 2048

#define SLOTS 34                  // px-slots per staged row (slot = xp-pxbase+1)
#define ROWE (SLOTS * 32)         // 1088 elems (2176 B) per row
#define BUFE (3 * ROWE)           // 3264 elems (6528 B) per buffer

typedef __attribute__((ext_vector_type(8))) short bf16x8;
typedef __attribute__((ext_vector_type(4))) float floatx4;

__device__ __forceinline__ unsigned short f2bf(float f) {
    unsigned int u; __builtin_memcpy(&u, &f, 4);
    unsigned int r = u + 0x7FFFu + ((u >> 16) & 1u);   // RNE
    return (unsigned short)(r >> 16);
}

__device__ __forceinline__ void async_copy16(const void* g, void* l) {
    __builtin_amdgcn_global_load_lds(
        (const __attribute__((address_space(1))) void*)g,
        (__attribute__((address_space(3))) void*)l, 16, 0, 0);
}

// ---------- transpose: fp32 x [b][c][hw] -> bf16 xT [b][hw][c] ----------
__global__ __launch_bounds__(256) void transpose_kernel(const float* __restrict__ x,
                                                        unsigned short* __restrict__ xT) {
    __shared__ unsigned short tile[32][80];
    int b = blockIdx.z, c0 = blockIdx.y * 32, px0 = blockIdx.x * 64;
    int t = threadIdx.x;
    int c_l = t >> 3, pxg = (t & 7) * 8;
    const float* sp = x + (long)(b * CIN + c0 + c_l) * HWDIM + px0 + pxg;
    float4 a = ((const float4*)sp)[0], bq = ((const float4*)sp)[1];
    tile[c_l][pxg + 0] = f2bf(a.x);  tile[c_l][pxg + 1] = f2bf(a.y);
    tile[c_l][pxg + 2] = f2bf(a.z);  tile[c_l][pxg + 3] = f2bf(a.w);
    tile[c_l][pxg + 4] = f2bf(bq.x); tile[c_l][pxg + 5] = f2bf(bq.y);
    tile[c_l][pxg + 6] = f2bf(bq.z); tile[c_l][pxg + 7] = f2bf(bq.w);
    __syncthreads();
    int px_l = t >> 2, cg = (t & 3) * 8;
    ushort4 o0, o1;
    o0.x = tile[cg + 0][px_l]; o0.y = tile[cg + 1][px_l];
    o0.z = tile[cg + 2][px_l]; o0.w = tile[cg + 3][px_l];
    o1.x = tile[cg + 4][px_l]; o1.y = tile[cg + 5][px_l];
    o1.z = tile[cg + 6][px_l]; o1.w = tile[cg + 7][px_l];
    long dst = (long)(b * HWDIM + px0 + px_l) * CIN + c0 + cg;
    *(ushort4*)(xT + dst) = o0;
    *(ushort4*)(xT + dst + 4) = o1;
}

// ---------- prep: BwT[tap][n(32,pad0)][c] bf16; BN fold (fp32 in) ----------
__global__ void prep_kernel(const float* __restrict__ w1,
                            const float* __restrict__ g, const float* __restrict__ bt,
                            const float* __restrict__ mn, const float* __restrict__ vr,
                            unsigned short* __restrict__ BwT,
                            float* __restrict__ scale, float* __restrict__ shift) {
    int idx = blockIdx.x * 256 + threadIdx.x;
    if (idx < 9 * 32 * 256) {
        int tap = idx >> 13;
        int r = idx & 8191;
        int n = r >> 8, c = r & 255;
        BwT[idx] = (n < PDIM) ? f2bf(w1[n * 2304 + c * 9 + tap]) : (unsigned short)0;
    } else if (idx < 73728 + 32) {
        int p = idx - 73728;
        if (p < PDIM) {
            float inv = g[p] / sqrtf(vr[p] + 1e-3f);
            scale[p] = inv;
            shift[p] = bt[p] - mn[p] * inv;
        } else { scale[p] = 0.f; shift[p] = 0.f; }
    }
}

// ---------- conv1: 1-wave blocks, barrier-free dbuf pipeline + epilogue ----------
// block = (b, y, win): win 0..4 -> 32 px (2 MFMA tiles), win 5 -> 16 px.
__global__ __launch_bounds__(64) void conv1_kernel(const unsigned short* __restrict__ xT,
                                                   const unsigned short* __restrict__ BwT,
                                                   const float* __restrict__ scale,
                                                   const float* __restrict__ shift,
                                                   const float* __restrict__ w2,
                                                   float* __restrict__ feat2) {
    // wave-private: As[buf 0..1][row 0..2][slot 0..33][c 0..31] bf16 = 13,056 B
    __shared__ unsigned short As[2 * BUFE];

    // XCD-chunked bijective swizzle over 4800 blocks (4800 % 8 == 0):
    // XCD k owns nl in [k*600, k*600+600) = 100 consecutive rows of one image.
    int wg = blockIdx.y * 1200 + blockIdx.x;
    int nl = (wg & 7) * 600 + (wg >> 3);
    int b = nl / 1200;
    int rem = nl - b * 1200;
    int y = rem / 6, win = rem - (rem / 6) * 6;
    int pxbase = win * 32;
    int nmt = (win == 5) ? 1 : 2;

    int lane = threadIdx.x;                 // 0..63
    int lm = lane & 15, kg = lane >> 4, kg8 = kg * 8;

    bool rowok[3];
#pragma unroll
    for (int rr = 0; rr < 3; rr++) rowok[rr] = (y + rr - 1 >= 0) && (y + rr - 1 < HDIM);

    // staging geometry: 3 segments of 16 px cover slots 0..33
    // (xp = pxbase-1+slot; clamped source, masked on read)
    const int s0tab[3] = {0, 16, 18};
    int segoff[3];                          // per-lane source offset (elements)
#pragma unroll
    for (int s = 0; s < 3; s++) {
        int xp = pxbase - 1 + s0tab[s] + (lane >> 2);
        xp = xp < 0 ? 0 : (xp > WDIM - 1 ? WDIM - 1 : xp);
        segoff[s] = xp * CIN + (lane & 3) * 8;
    }
    const unsigned short* rbaseg[3];        // uniform row bases (y-clamped)
#pragma unroll
    for (int rr = 0; rr < 3; rr++) {
        int yp = y + rr - 1;
        yp = yp < 0 ? 0 : (yp > HDIM - 1 ? HDIM - 1 : yp);
        rbaseg[rr] = xT + (long)(b * HDIM + yp) * WDIM * CIN;
    }

    // per-(mt,d) LDS element offset of this lane's A fragment + validity
    int  aoff[2][3];
    bool xval[2][3];
#pragma unroll
    for (int mt = 0; mt < 2; mt++) {
#pragma unroll
        for (int d = 0; d < 3; d++) {
            int xp = pxbase + mt * 16 + lm + (d - 1);
            xval[mt][d] = (xp >= 0) && (xp < WDIM);
            aoff[mt][d] = (mt * 16 + lm + d) * 32 + kg8;   // slot*32 + kg8
        }
    }

    // prologue: stage chunk 0 -> buf0 (always 9 loads)
#pragma unroll
    for (int rr = 0; rr < 3; rr++)
#pragma unroll
        for (int s = 0; s < 3; s++)
            async_copy16(rbaseg[rr] + segoff[s], &As[rr * ROWE + s0tab[s] * 32]);

    floatx4 acc[2][2] = {{{0.f,0.f,0.f,0.f},{0.f,0.f,0.f,0.f}},
                         {{0.f,0.f,0.f,0.f},{0.f,0.f,0.f,0.f}}};

    for (int j = 0; j < 8; j++) {
        int cofs = j * 32 + kg8;
        // B fragments first (18 loads; compiler's counted waits for these
        // never drain the stage loads issued after them)
        bf16x8 bfr[9][2];
#pragma unroll
        for (int tap = 0; tap < 9; tap++) {
            const unsigned short* bp = BwT + ((tap * 32 + lm) << 8) + cofs;
            bfr[tap][0] = *(const bf16x8*)bp;
            bfr[tap][1] = *(const bf16x8*)(bp + 4096);   // n-tile 1
        }
        // stage chunk j+1 into the other buffer (9 loads, stays in flight
        // across the entire compute phase below)
        if (j < 7) {
            unsigned short* dst = &As[((j + 1) & 1) * BUFE];
            int joff = (j + 1) * 32;
#pragma unroll
            for (int rr = 0; rr < 3; rr++)
#pragma unroll
                for (int s = 0; s < 3; s++)
                    async_copy16(rbaseg[rr] + segoff[s] + joff,
                                 dst + rr * ROWE + s0tab[s] * 32);
            // wait for chunk j's 9 stage loads: exactly 27 younger vmem ops
            asm volatile("s_waitcnt vmcnt(27)" ::: "memory");
        } else {
            asm volatile("s_waitcnt vmcnt(18)" ::: "memory");
        }
        __builtin_amdgcn_sched_barrier(0);

        const unsigned short* cur = &As[(j & 1) * BUFE];
#pragma unroll
        for (int tap = 0; tap < 9; tap++) {
            int rr = tap / 3, d = tap % 3;
            if (!rowok[rr]) continue;           // block-uniform
            const unsigned short* rbase = cur + rr * ROWE;
#pragma unroll
            for (int mt = 0; mt < 2; mt++) {
                if (mt < nmt) {
                    bf16x8 afr = *(const bf16x8*)&rbase[aoff[mt][d]];
                    if (!xval[mt][d]) afr = (bf16x8)0;
                    acc[mt][0] = __builtin_amdgcn_mfma_f32_16x16x32_bf16(afr, bfr[tap][0], acc[mt][0], 0, 0, 0);
                    acc[mt][1] = __builtin_amdgcn_mfma_f32_16x16x32_bf16(afr, bfr[tap][1], acc[mt][1], 0, 0, 0);
                }
            }
        }
    }

    // ---- epilogue: BN + relu -> wave-private LDS tile -> fp32 conv2 matvec ----
    // t2 tile (16x36 f32 = 2304 B) aliases buf0 (dead: last compute used buf1).
    float* t2f = (float*)As;
#define T2(R, N) t2f[(R) * 36 + (N)]
    long rowpix = (long)b * HWDIM + (long)y * WDIM;
    int n_l = lane & 31;           // output channel handled by this lane (<28 valid)
    int hlf = lane >> 5;           // lanes 0-31 do px 0-7, lanes 32-63 do px 8-15
    float4 w2r[7];
#pragma unroll
    for (int jj = 0; jj < 7; jj++) {
        if (n_l < PDIM) w2r[jj] = ((const float4*)(w2 + n_l * PDIM))[jj];
        else            w2r[jj] = make_float4(0.f, 0.f, 0.f, 0.f);
    }

#pragma unroll
    for (int mt = 0; mt < 2; mt++) {
        if (mt < nmt) {
#pragma unroll
            for (int nt = 0; nt < 2; nt++) {
                int n = nt * 16 + lm;
                float sc = scale[n], sh2 = shift[n];
#pragma unroll
                for (int rg = 0; rg < 4; rg++) {
                    float v = fmaf(acc[mt][nt][rg], sc, sh2);
                    T2(kg * 4 + rg, n) = v > 0.f ? v : 0.f;
                }
            }
            // wave-internal LDS dependency: compiler inserts lgkmcnt waits.
#pragma unroll
            for (int i = 0; i < 8; i++) {
                int pxl = hlf * 8 + i;
                float s = 0.f;
#pragma unroll
                for (int jj = 0; jj < 7; jj++) {
                    float4 a = *(const float4*)&T2(pxl, jj * 4);
                    s = fmaf(a.x, w2r[jj].x, s); s = fmaf(a.y, w2r[jj].y, s);
                    s = fmaf(a.z, w2r[jj].z, s); s = fmaf(a.w, w2r[jj].w, s);
                }
                int px = pxbase + mt * 16 + pxl;
                if (n_l < PDIM) feat2[(rowpix + px) * PDIM + n_l] = s;
            }
        }
    }
#undef T2
}

// ---------- PS bilinear sampler on precomputed conv2 output (scalar gather) ----------
__global__ __launch_bounds__(256) void sample_kernel(const float* __restrict__ boxes,
                                                     const float* __restrict__ feat2,
                                                     float* __restrict__ out) {
    int gid = blockIdx.x * 256 + threadIdx.x;
    int box = gid >> 5;              // 32 lanes per box
    int pl = gid & 31;
    int b = box >> 11;
    float val = 0.f;
    if (pl < PDIM) {
        long bb = (long)box * 7;
        float xg = boxes[bb + 0], yg = boxes[bb + 1];
        float wg = boxes[bb + 3], lg = boxes[bb + 4];
        float rg = boxes[bb + 6];
        float ct = cosf(rg), st = sinf(rg);
        const float lxv[4] = {-0.5f, -0.16666667f, 0.16666667f, 0.5f};
        const float lyv[7] = {-0.5f, -0.33333334f, -0.16666667f, 0.f,
                               0.16666667f, 0.33333334f, 0.5f};
        int h = pl / 7, ww = pl - (pl / 7) * 7;
        float xx = lxv[h] * wg;
        float yy = lyv[ww] * lg;
        float gx = (xx * ct + yy * st + xg) * 2.5f;           // GRID_OFF.x = 0
        float gy = (yy * ct - xx * st + yg + 40.f) * 2.5f;    // GRID_OFF.y = 40
        float x0 = floorf(gx), y0 = floorf(gy);
        float fx = gx - x0, fy = gy - y0;
        int xi = (int)x0, yi = (int)y0;
        const float* base = feat2 + (long)b * HWDIM * PDIM + pl;
        float Ia = 0.f, Ib = 0.f, Ic = 0.f, Id = 0.f;
        if (yi >= 0 && yi < HDIM) {
            long r0 = (long)yi * WDIM;
            if (xi >= 0 && xi < WDIM)         Ia = base[(r0 + xi) * PDIM];
            if (xi + 1 >= 0 && xi + 1 < WDIM) Ic = base[(r0 + xi + 1) * PDIM];
        }
        if (yi + 1 >= 0 && yi + 1 < HDIM) {
            long r1 = (long)(yi + 1) * WDIM;
            if (xi >= 0 && xi < WDIM)         Ib = base[(r1 + xi) * PDIM];
            if (xi + 1 >= 0 && xi + 1 < WDIM) Id = base[(r1 + xi + 1) * PDIM];
        }
        val = (1.f - fx) * (1.f - fy) * Ia + (1.f - fx) * fy * Ib
            + fx * (1.f - fy) * Ic + fx * fy * Id;
    }
#pragma unroll
    for (int m = 16; m >= 1; m >>= 1) val += __shfl_xor(val, m, 64);
    if ((threadIdx.x & 31) == 0) {
        out[box] = val * (1.f / 28.f);
    }
}

// ---------- launch ----------
extern "C" void kernel_launch(void* const* d_in, const int* in_sizes, int n_in,
                              void* d_out, int out_size, void* d_ws, size_t ws_size,
                              hipStream_t stream) {
    const float* x     = (const float*)d_in[0];
    const float* boxes = (const float*)d_in[1];
    const float* w1    = (const float*)d_in[2];
    const float* g     = (const float*)d_in[3];
    const float* bt    = (const float*)d_in[4];
    const float* mn    = (const float*)d_in[5];
    const float* vr    = (const float*)d_in[6];
    const float* w2    = (const float*)d_in[7];
    float* out = (float*)d_out;

    char* ws = (char*)d_ws;
    unsigned short* xT  = (unsigned short*)ws;                 // 72,089,600 B
    float* feat2        = (float*)(ws + 72089600);             // 15,769,600 B
    unsigned short* BwT = (unsigned short*)(ws + 90112000);    //    147,456 B
    float* scale        = (float*)(ws + 90259456);             //        128 B
    float* shift        = (float*)(ws + 90259584);             //        128 B

    transpose_kernel<<<dim3(550, 8, 4), 256, 0, stream>>>(x, xT);
    prep_kernel<<<289, 256, 0, stream>>>(w1, g, bt, mn, vr, BwT, scale, shift);
    conv1_kernel<<<dim3(1200, 4), 64, 0, stream>>>(xT, BwT, scale, shift, w2, feat2);
    sample_kernel<<<1024, 256, 0, stream>>>(boxes, feat2, out);
}

// Round 6
// 284.692 us; speedup vs baseline: 1.3979x; 1.2026x over previous
//
#include <hip/hip_runtime.h>
#include <hip/hip_bf16.h>

// PSWarpHead round 12. conv1: registers-only 32x32x16 MFMA pipeline.
//   r11 post-mortem: per-block issue ~7K cyc vs ~160K cyc lifetime; vmcnt
//   retires IN ORDER so B-loads issued after stage loads forced stage drains
//   (pipeline never overlapped); B loads were 16-way scattered.
//   Fix: fragment-contiguous layouts so every load = 1 coalesced KB:
//     xT2[b][ksub 0..15][hw][16c]  (A frag of mfma_32x32x16 contiguous)
//     BwT2[tap*16+ksub][lane 0..63][8c] (B frag contiguous)
//   conv1: 16 k-steps; A reg-dbuf (2x9 frags); B same-step issued BEFORE
//   A-next (in-order retirement => waiting B never drains A-next); manual
//   vmcnt(18)/vmcnt(9) + sched_barrier(0); NO LDS/barriers in main loop.
//   9 MFMA 32x32x16 per step (half the instr count of r11).
//   Epilogue: BN+relu+conv2 matvec via 4.6KB LDS tile -> feat2[px][28].
//   sample unchanged (r7-validated).
// Loads always 9+9 per step (clamped addrs; invalid rows/lanes masked at
// MFMA) so waitcnt constants are exact. 4800 blocks, bijective XCD swizzle.

#define WDIM 176
#define HDIM 200
#define HWDIM 35200
#define CIN 256
#define PDIM 28
#define NBOX 2048

typedef __attribute__((ext_vector_type(8))) short bf16x8;
typedef __attribute__((ext_vector_type(4))) float floatx4;
typedef __attribute__((ext_vector_type(16))) float floatx16;

__device__ __forceinline__ unsigned short f2bf(float f) {
    unsigned int u; __builtin_memcpy(&u, &f, 4);
    unsigned int r = u + 0x7FFFu + ((u >> 16) & 1u);   // RNE
    return (unsigned short)(r >> 16);
}

// ---------- transpose: fp32 x [b][c][hw] -> bf16 xT2 [b][ksub][hw][16c] ----------
__global__ __launch_bounds__(256) void transpose_kernel(const float* __restrict__ x,
                                                        unsigned short* __restrict__ xT2) {
    __shared__ unsigned short tile[32][80];
    int b = blockIdx.z, c0 = blockIdx.y * 32, px0 = blockIdx.x * 64;
    int t = threadIdx.x;
    int c_l = t >> 3, pxg = (t & 7) * 8;
    const float* sp = x + (long)(b * CIN + c0 + c_l) * HWDIM + px0 + pxg;
    float4 a = ((const float4*)sp)[0], bq = ((const float4*)sp)[1];
    tile[c_l][pxg + 0] = f2bf(a.x);  tile[c_l][pxg + 1] = f2bf(a.y);
    tile[c_l][pxg + 2] = f2bf(a.z);  tile[c_l][pxg + 3] = f2bf(a.w);
    tile[c_l][pxg + 4] = f2bf(bq.x); tile[c_l][pxg + 5] = f2bf(bq.y);
    tile[c_l][pxg + 6] = f2bf(bq.z); tile[c_l][pxg + 7] = f2bf(bq.w);
    __syncthreads();
    int px_l = t >> 2, cg = (t & 3) * 8;       // cg in {0,8,16,24}
    ushort4 o0, o1;
    o0.x = tile[cg + 0][px_l]; o0.y = tile[cg + 1][px_l];
    o0.z = tile[cg + 2][px_l]; o0.w = tile[cg + 3][px_l];
    o1.x = tile[cg + 4][px_l]; o1.y = tile[cg + 5][px_l];
    o1.z = tile[cg + 6][px_l]; o1.w = tile[cg + 7][px_l];
    int ks = (c0 + cg) >> 4;                   // ksub plane
    int co = cg & 8;                           // c offset within ksub
    long dst = ((long)(b * 16 + ks) * HWDIM + px0 + px_l) * 16 + co;
    *(ushort4*)(xT2 + dst) = o0;
    *(ushort4*)(xT2 + dst + 4) = o1;
}

// ---------- prep: BwT2[f=tap*16+ks][lane=kh*32+n][8c] bf16; BN fold ----------
__global__ void prep_kernel(const float* __restrict__ w1,
                            const float* __restrict__ g, const float* __restrict__ bt,
                            const float* __restrict__ mn, const float* __restrict__ vr,
                            unsigned short* __restrict__ BwT2,
                            float* __restrict__ scale, float* __restrict__ shift) {
    int idx = blockIdx.x * 256 + threadIdx.x;
    if (idx < 9 * 16 * 64 * 8) {               // 73728
        int f = idx >> 9;                      // 512 elems per fragment
        int tap = f >> 4, ks = f & 15;
        int l = (idx >> 3) & 63;
        int e = idx & 7;
        int n = l & 31, kh = l >> 5;
        int c = ks * 16 + kh * 8 + e;
        BwT2[idx] = (n < PDIM) ? f2bf(w1[n * 2304 + c * 9 + tap]) : (unsigned short)0;
    } else if (idx < 73728 + 32) {
        int p = idx - 73728;
        if (p < PDIM) {
            float inv = g[p] / sqrtf(vr[p] + 1e-3f);
            scale[p] = inv;
            shift[p] = bt[p] - mn[p] * inv;
        } else { scale[p] = 0.f; shift[p] = 0.f; }
    }
}

// ---------- conv1: registers-only 32x32x16 MFMA pipeline + fused epilogue ----------
// block = (b, y, win): 1 wave, window = 32 px (win5: 16 valid, rest masked).
__global__ __launch_bounds__(64) void conv1_kernel(const unsigned short* __restrict__ xT2,
                                                   const unsigned short* __restrict__ BwT2,
                                                   const float* __restrict__ scale,
                                                   const float* __restrict__ shift,
                                                   const float* __restrict__ w2,
                                                   float* __restrict__ feat2) {
    __shared__ float t2f[32 * 36];             // epilogue tile [32 px][36]

    // XCD-chunked bijective swizzle over 4800 blocks (4800 % 8 == 0)
    int wg = blockIdx.y * 1200 + blockIdx.x;
    int nl = (wg & 7) * 600 + (wg >> 3);
    int b = nl / 1200;
    int rem = nl - b * 1200;
    int y = rem / 6, win = rem - (rem / 6) * 6;
    int pxbase = win * 32;

    int lane = threadIdx.x;
    int r32 = lane & 31, khalf = lane >> 5;

    bool rowok[3];
#pragma unroll
    for (int rr = 0; rr < 3; rr++) rowok[rr] = (y + rr - 1 >= 0) && (y + rr - 1 < HDIM);
    bool edge = (win == 0) || (win == 5);      // only these have invalid px lanes

    // per-d lane validity + byte voffset into a ksub plane row
    bool xval[3];
    int  voff[3];
#pragma unroll
    for (int d = 0; d < 3; d++) {
        int xp = pxbase + r32 + d - 1;
        xval[d] = (xp >= 0) && (xp < WDIM);
        int xc = xp < 0 ? 0 : (xp > WDIM - 1 ? WDIM - 1 : xp);
        voff[d] = xc * 32 + khalf * 16;        // px*32B + khalf*16B
    }

    // block-uniform row bases (ks=0 plane), y-clamped; KS = ksub plane stride
    const char* abase[3];
#pragma unroll
    for (int rr = 0; rr < 3; rr++) {
        int yc = y + rr - 1;
        yc = yc < 0 ? 0 : (yc > HDIM - 1 ? HDIM - 1 : yc);
        abase[rr] = (const char*)xT2 + ((long)b * 16 * HWDIM + (long)yc * WDIM) * 32;
    }
    const long KS = (long)HWDIM * 32;          // 1,126,400 B per ksub plane
    const char* bb = (const char*)BwT2 + lane * 16;

    // prologue: A fragments for step 0
    bf16x8 aq[2][9];
#pragma unroll
    for (int t = 0; t < 9; t++)
        aq[0][t] = *(const bf16x8*)(abase[t / 3] + voff[t % 3]);

    floatx16 acc = {};

#pragma unroll
    for (int s = 0; s < 16; s++) {
        const int cur = s & 1, nxt = cur ^ 1;
        // B fragments for step s (issued BEFORE A-next: in-order vmcnt
        // retirement means waiting on these never drains A-next)
        bf16x8 bq[9];
#pragma unroll
        for (int t = 0; t < 9; t++)
            bq[t] = *(const bf16x8*)(bb + t * 16384 + s * 1024);
        if (s < 15) {
            // A fragments for step s+1 (9 loads, in flight through the MFMAs)
#pragma unroll
            for (int t = 0; t < 9; t++)
                aq[nxt][t] = *(const bf16x8*)(abase[t / 3] + KS * (s + 1) + voff[t % 3]);
            __builtin_amdgcn_sched_barrier(0);
            asm volatile("s_waitcnt vmcnt(18)" ::: "memory");   // A(s) done
        } else {
            __builtin_amdgcn_sched_barrier(0);
            asm volatile("s_waitcnt vmcnt(9)" ::: "memory");    // A(15) done
        }
        __builtin_amdgcn_sched_barrier(0);
        if (!edge) {
#pragma unroll
            for (int t = 0; t < 9; t++) {
                if (!rowok[t / 3]) continue;   // block-uniform
                acc = __builtin_amdgcn_mfma_f32_32x32x16_bf16(aq[cur][t], bq[t], acc, 0, 0, 0);
            }
        } else {
#pragma unroll
            for (int t = 0; t < 9; t++) {
                if (!rowok[t / 3]) continue;   // block-uniform
                bf16x8 af = aq[cur][t];
                if (!xval[t % 3]) af = (bf16x8)0;
                acc = __builtin_amdgcn_mfma_f32_32x32x16_bf16(af, bq[t], acc, 0, 0, 0);
            }
        }
    }

    // ---- epilogue: BN + relu -> LDS tile -> fp32 conv2 matvec ----
    // acc C/D (32x32): col n = lane&31, row px = (reg&3)+8*(reg>>2)+4*(lane>>5)
    {
        float sc = scale[r32], sh2 = shift[r32];
#pragma unroll
        for (int i = 0; i < 16; i++) {
            int prow = (i & 3) + 8 * (i >> 2) + 4 * khalf;
            float v = fmaf(acc[i], sc, sh2);
            t2f[prow * 36 + r32] = v > 0.f ? v : 0.f;
        }
    }
    long rowpix = (long)b * HWDIM + (long)y * WDIM;
    int n_l = r32;                 // output channel (<28 valid)
    float4 w2r[7];
#pragma unroll
    for (int jj = 0; jj < 7; jj++) {
        if (n_l < PDIM) w2r[jj] = ((const float4*)(w2 + n_l * PDIM))[jj];
        else            w2r[jj] = make_float4(0.f, 0.f, 0.f, 0.f);
    }
    // wave-internal LDS dependency: compiler inserts lgkmcnt waits.
#pragma unroll
    for (int i = 0; i < 16; i++) {
        int pxl = khalf * 16 + i;              // lanes 0-31: px 0-15; 32-63: 16-31
        float s = 0.f;
#pragma unroll
        for (int jj = 0; jj < 7; jj++) {
            float4 a = *(const float4*)&t2f[pxl * 36 + jj * 4];
            s = fmaf(a.x, w2r[jj].x, s); s = fmaf(a.y, w2r[jj].y, s);
            s = fmaf(a.z, w2r[jj].z, s); s = fmaf(a.w, w2r[jj].w, s);
        }
        int px = pxbase + pxl;
        if (n_l < PDIM && px < WDIM) feat2[(rowpix + px) * PDIM + n_l] = s;
    }
}

// ---------- PS bilinear sampler on precomputed conv2 output (scalar gather) ----------
__global__ __launch_bounds__(256) void sample_kernel(const float* __restrict__ boxes,
                                                     const float* __restrict__ feat2,
                                                     float* __restrict__ out) {
    int gid = blockIdx.x * 256 + threadIdx.x;
    int box = gid >> 5;              // 32 lanes per box
    int pl = gid & 31;
    int b = box >> 11;
    float val = 0.f;
    if (pl < PDIM) {
        long bb = (long)box * 7;
        float xg = boxes[bb + 0], yg = boxes[bb + 1];
        float wg = boxes[bb + 3], lg = boxes[bb + 4];
        float rg = boxes[bb + 6];
        float ct = cosf(rg), st = sinf(rg);
        const float lxv[4] = {-0.5f, -0.16666667f, 0.16666667f, 0.5f};
        const float lyv[7] = {-0.5f, -0.33333334f, -0.16666667f, 0.f,
                               0.16666667f, 0.33333334f, 0.5f};
        int h = pl / 7, ww = pl - (pl / 7) * 7;
        float xx = lxv[h] * wg;
        float yy = lyv[ww] * lg;
        float gx = (xx * ct + yy * st + xg) * 2.5f;           // GRID_OFF.x = 0
        float gy = (yy * ct - xx * st + yg + 40.f) * 2.5f;    // GRID_OFF.y = 40
        float x0 = floorf(gx), y0 = floorf(gy);
        float fx = gx - x0, fy = gy - y0;
        int xi = (int)x0, yi = (int)y0;
        const float* base = feat2 + (long)b * HWDIM * PDIM + pl;
        float Ia = 0.f, Ib = 0.f, Ic = 0.f, Id = 0.f;
        if (yi >= 0 && yi < HDIM) {
            long r0 = (long)yi * WDIM;
            if (xi >= 0 && xi < WDIM)         Ia = base[(r0 + xi) * PDIM];
            if (xi + 1 >= 0 && xi + 1 < WDIM) Ic = base[(r0 + xi + 1) * PDIM];
        }
        if (yi + 1 >= 0 && yi + 1 < HDIM) {
            long r1 = (long)(yi + 1) * WDIM;
            if (xi >= 0 && xi < WDIM)         Ib = base[(r1 + xi) * PDIM];
            if (xi + 1 >= 0 && xi + 1 < WDIM) Id = base[(r1 + xi + 1) * PDIM];
        }
        val = (1.f - fx) * (1.f - fy) * Ia + (1.f - fx) * fy * Ib
            + fx * (1.f - fy) * Ic + fx * fy * Id;
    }
#pragma unroll
    for (int m = 16; m >= 1; m >>= 1) val += __shfl_xor(val, m, 64);
    if ((threadIdx.x & 31) == 0) {
        out[box] = val * (1.f / 28.f);
    }
}

// ---------- launch ----------
extern "C" void kernel_launch(void* const* d_in, const int* in_sizes, int n_in,
                              void* d_out, int out_size, void* d_ws, size_t ws_size,
                              hipStream_t stream) {
    const float* x     = (const float*)d_in[0];
    const float* boxes = (const float*)d_in[1];
    const float* w1    = (const float*)d_in[2];
    const float* g     = (const float*)d_in[3];
    const float* bt    = (const float*)d_in[4];
    const float* mn    = (const float*)d_in[5];
    const float* vr    = (const float*)d_in[6];
    const float* w2    = (const float*)d_in[7];
    float* out = (float*)d_out;

    char* ws = (char*)d_ws;
    unsigned short* xT2  = (unsigned short*)ws;                // 72,089,600 B
    float* feat2         = (float*)(ws + 72089600);            // 15,769,600 B
    unsigned short* BwT2 = (unsigned short*)(ws + 90112000);   //    147,456 B
    float* scale         = (float*)(ws + 90259456);            //        128 B
    float* shift         = (float*)(ws + 90259584);            //        128 B

    transpose_kernel<<<dim3(550, 8, 4), 256, 0, stream>>>(x, xT2);
    prep_kernel<<<289, 256, 0, stream>>>(w1, g, bt, mn, vr, BwT2, scale, shift);
    conv1_kernel<<<dim3(1200, 4), 64, 0, stream>>>(xT2, BwT2, scale, shift, w2, feat2);
    sample_kernel<<<1024, 256, 0, stream>>>(boxes, feat2, out);
}

// Round 7
// 284.230 us; speedup vs baseline: 1.4002x; 1.0016x over previous
//
#include <hip/hip_runtime.h>
#include <hip/hip_bf16.h>

// PSWarpHead round 13. Transpose write-coalescing fix.
//   r12 post-mortem: conv1 ~48us (register-only pipeline worked); top-5 now
//   all harness fillBuffer (84us). Remainder ~237us invariant. New suspect:
//   r12's transpose writes 32x16B scattered segments per wave (two ksub
//   planes 1.1MB apart, 8B granules) -> <=25% write-sector efficiency.
//   Fix: 64px x 64c tiles; phase1 reads 64B/lane contiguous fp32 -> LDS
//   [px][c] (pad 72, b128-aligned); phase2 wave w = one ksub plane, lane l
//   writes 16B at l*16 -> every store inst = contiguous 1KB wave-write.
//   xT2 bytes identical to r12 (same f2bf) -> absmax unchanged.
//   conv1 (r12 registers-only 32x32x16 MFMA) / prep / sample unchanged.

#define WDIM 176
#define HDIM 200
#define HWDIM 35200
#define CIN 256
#define PDIM 28
#define NBOX 2048

typedef __attribute__((ext_vector_type(8))) short bf16x8;
typedef __attribute__((ext_vector_type(4))) float floatx4;
typedef __attribute__((ext_vector_type(16))) float floatx16;

__device__ __forceinline__ unsigned short f2bf(float f) {
    unsigned int u; __builtin_memcpy(&u, &f, 4);
    unsigned int r = u + 0x7FFFu + ((u >> 16) & 1u);   // RNE
    return (unsigned short)(r >> 16);
}

// ---------- transpose: fp32 x [b][c][hw] -> bf16 xT2 [b][ksub][hw][16c] ----------
// 64px x 64c tile, 256 thr. Phase2 writes are 1KB-contiguous per wave-inst.
__global__ __launch_bounds__(256) void transpose_kernel(const float* __restrict__ x,
                                                        unsigned short* __restrict__ xT2) {
    __shared__ unsigned short st[64][72];      // [px][c], pad 72 (144B rows, 16B-aligned)
    int b = blockIdx.z, c0 = blockIdx.y * 64, px0 = blockIdx.x * 64;
    int t = threadIdx.x;

    // phase 1: thread reads 16 px of one channel (64B contiguous), converts
    int c_l = t >> 2, pq = t & 3;
    const float* sp = x + (long)(b * CIN + c0 + c_l) * HWDIM + px0 + pq * 16;
    float4 v0 = ((const float4*)sp)[0], v1 = ((const float4*)sp)[1];
    float4 v2 = ((const float4*)sp)[2], v3 = ((const float4*)sp)[3];
    int pr = pq * 16;
    st[pr +  0][c_l] = f2bf(v0.x); st[pr +  1][c_l] = f2bf(v0.y);
    st[pr +  2][c_l] = f2bf(v0.z); st[pr +  3][c_l] = f2bf(v0.w);
    st[pr +  4][c_l] = f2bf(v1.x); st[pr +  5][c_l] = f2bf(v1.y);
    st[pr +  6][c_l] = f2bf(v1.z); st[pr +  7][c_l] = f2bf(v1.w);
    st[pr +  8][c_l] = f2bf(v2.x); st[pr +  9][c_l] = f2bf(v2.y);
    st[pr + 10][c_l] = f2bf(v2.z); st[pr + 11][c_l] = f2bf(v2.w);
    st[pr + 12][c_l] = f2bf(v3.x); st[pr + 13][c_l] = f2bf(v3.y);
    st[pr + 14][c_l] = f2bf(v3.z); st[pr + 15][c_l] = f2bf(v3.w);
    __syncthreads();

    // phase 2: wave w -> ksub plane (c0/16 + w); lane l -> px i*32+(l>>1),
    // half-16c (l&1). Store addr = base + l*16 -> contiguous 1KB per inst.
    int w = t >> 6, l = t & 63;
    int ks = (c0 >> 4) + w;
    long pbase = ((long)(b * 16 + ks) * HWDIM + px0) * 16;
#pragma unroll
    for (int i = 0; i < 2; i++) {
        int px_l = i * 32 + (l >> 1);
        int hc = l & 1;
        bf16x8 frag = *(const bf16x8*)&st[px_l][w * 16 + hc * 8];
        *(bf16x8*)(xT2 + pbase + px_l * 16 + hc * 8) = frag;
    }
}

// ---------- prep: BwT2[f=tap*16+ks][lane=kh*32+n][8c] bf16; BN fold ----------
__global__ void prep_kernel(const float* __restrict__ w1,
                            const float* __restrict__ g, const float* __restrict__ bt,
                            const float* __restrict__ mn, const float* __restrict__ vr,
                            unsigned short* __restrict__ BwT2,
                            float* __restrict__ scale, float* __restrict__ shift) {
    int idx = blockIdx.x * 256 + threadIdx.x;
    if (idx < 9 * 16 * 64 * 8) {               // 73728
        int f = idx >> 9;                      // 512 elems per fragment
        int tap = f >> 4, ks = f & 15;
        int l = (idx >> 3) & 63;
        int e = idx & 7;
        int n = l & 31, kh = l >> 5;
        int c = ks * 16 + kh * 8 + e;
        BwT2[idx] = (n < PDIM) ? f2bf(w1[n * 2304 + c * 9 + tap]) : (unsigned short)0;
    } else if (idx < 73728 + 32) {
        int p = idx - 73728;
        if (p < PDIM) {
            float inv = g[p] / sqrtf(vr[p] + 1e-3f);
            scale[p] = inv;
            shift[p] = bt[p] - mn[p] * inv;
        } else { scale[p] = 0.f; shift[p] = 0.f; }
    }
}

// ---------- conv1: registers-only 32x32x16 MFMA pipeline + fused epilogue ----------
// block = (b, y, win): 1 wave, window = 32 px (win5: 16 valid, rest masked).
__global__ __launch_bounds__(64) void conv1_kernel(const unsigned short* __restrict__ xT2,
                                                   const unsigned short* __restrict__ BwT2,
                                                   const float* __restrict__ scale,
                                                   const float* __restrict__ shift,
                                                   const float* __restrict__ w2,
                                                   float* __restrict__ feat2) {
    __shared__ float t2f[32 * 36];             // epilogue tile [32 px][36]

    // XCD-chunked bijective swizzle over 4800 blocks (4800 % 8 == 0)
    int wg = blockIdx.y * 1200 + blockIdx.x;
    int nl = (wg & 7) * 600 + (wg >> 3);
    int b = nl / 1200;
    int rem = nl - b * 1200;
    int y = rem / 6, win = rem - (rem / 6) * 6;
    int pxbase = win * 32;

    int lane = threadIdx.x;
    int r32 = lane & 31, khalf = lane >> 5;

    bool rowok[3];
#pragma unroll
    for (int rr = 0; rr < 3; rr++) rowok[rr] = (y + rr - 1 >= 0) && (y + rr - 1 < HDIM);
    bool edge = (win == 0) || (win == 5);      // only these have invalid px lanes

    // per-d lane validity + byte voffset into a ksub plane row
    bool xval[3];
    int  voff[3];
#pragma unroll
    for (int d = 0; d < 3; d++) {
        int xp = pxbase + r32 + d - 1;
        xval[d] = (xp >= 0) && (xp < WDIM);
        int xc = xp < 0 ? 0 : (xp > WDIM - 1 ? WDIM - 1 : xp);
        voff[d] = xc * 32 + khalf * 16;        // px*32B + khalf*16B
    }

    // block-uniform row bases (ks=0 plane), y-clamped; KS = ksub plane stride
    const char* abase[3];
#pragma unroll
    for (int rr = 0; rr < 3; rr++) {
        int yc = y + rr - 1;
        yc = yc < 0 ? 0 : (yc > HDIM - 1 ? HDIM - 1 : yc);
        abase[rr] = (const char*)xT2 + ((long)b * 16 * HWDIM + (long)yc * WDIM) * 32;
    }
    const long KS = (long)HWDIM * 32;          // 1,126,400 B per ksub plane
    const char* bb = (const char*)BwT2 + lane * 16;

    // prologue: A fragments for step 0
    bf16x8 aq[2][9];
#pragma unroll
    for (int t = 0; t < 9; t++)
        aq[0][t] = *(const bf16x8*)(abase[t / 3] + voff[t % 3]);

    floatx16 acc = {};

#pragma unroll
    for (int s = 0; s < 16; s++) {
        const int cur = s & 1, nxt = cur ^ 1;
        // B fragments for step s (issued BEFORE A-next: in-order vmcnt
        // retirement means waiting on these never drains A-next)
        bf16x8 bq[9];
#pragma unroll
        for (int t = 0; t < 9; t++)
            bq[t] = *(const bf16x8*)(bb + t * 16384 + s * 1024);
        if (s < 15) {
            // A fragments for step s+1 (9 loads, in flight through the MFMAs)
#pragma unroll
            for (int t = 0; t < 9; t++)
                aq[nxt][t] = *(const bf16x8*)(abase[t / 3] + KS * (s + 1) + voff[t % 3]);
            __builtin_amdgcn_sched_barrier(0);
            asm volatile("s_waitcnt vmcnt(18)" ::: "memory");   // A(s) done
        } else {
            __builtin_amdgcn_sched_barrier(0);
            asm volatile("s_waitcnt vmcnt(9)" ::: "memory");    // A(15) done
        }
        __builtin_amdgcn_sched_barrier(0);
        if (!edge) {
#pragma unroll
            for (int t = 0; t < 9; t++) {
                if (!rowok[t / 3]) continue;   // block-uniform
                acc = __builtin_amdgcn_mfma_f32_32x32x16_bf16(aq[cur][t], bq[t], acc, 0, 0, 0);
            }
        } else {
#pragma unroll
            for (int t = 0; t < 9; t++) {
                if (!rowok[t / 3]) continue;   // block-uniform
                bf16x8 af = aq[cur][t];
                if (!xval[t % 3]) af = (bf16x8)0;
                acc = __builtin_amdgcn_mfma_f32_32x32x16_bf16(af, bq[t], acc, 0, 0, 0);
            }
        }
    }

    // ---- epilogue: BN + relu -> LDS tile -> fp32 conv2 matvec ----
    // acc C/D (32x32): col n = lane&31, row px = (reg&3)+8*(reg>>2)+4*(lane>>5)
    {
        float sc = scale[r32], sh2 = shift[r32];
#pragma unroll
        for (int i = 0; i < 16; i++) {
            int prow = (i & 3) + 8 * (i >> 2) + 4 * khalf;
            float v = fmaf(acc[i], sc, sh2);
            t2f[prow * 36 + r32] = v > 0.f ? v : 0.f;
        }
    }
    long rowpix = (long)b * HWDIM + (long)y * WDIM;
    int n_l = r32;                 // output channel (<28 valid)
    float4 w2r[7];
#pragma unroll
    for (int jj = 0; jj < 7; jj++) {
        if (n_l < PDIM) w2r[jj] = ((const float4*)(w2 + n_l * PDIM))[jj];
        else            w2r[jj] = make_float4(0.f, 0.f, 0.f, 0.f);
    }
    // wave-internal LDS dependency: compiler inserts lgkmcnt waits.
#pragma unroll
    for (int i = 0; i < 16; i++) {
        int pxl = khalf * 16 + i;              // lanes 0-31: px 0-15; 32-63: 16-31
        float s = 0.f;
#pragma unroll
        for (int jj = 0; jj < 7; jj++) {
            float4 a = *(const float4*)&t2f[pxl * 36 + jj * 4];
            s = fmaf(a.x, w2r[jj].x, s); s = fmaf(a.y, w2r[jj].y, s);
            s = fmaf(a.z, w2r[jj].z, s); s = fmaf(a.w, w2r[jj].w, s);
        }
        int px = pxbase + pxl;
        if (n_l < PDIM && px < WDIM) feat2[(rowpix + px) * PDIM + n_l] = s;
    }
}

// ---------- PS bilinear sampler on precomputed conv2 output (scalar gather) ----------
__global__ __launch_bounds__(256) void sample_kernel(const float* __restrict__ boxes,
                                                     const float* __restrict__ feat2,
                                                     float* __restrict__ out) {
    int gid = blockIdx.x * 256 + threadIdx.x;
    int box = gid >> 5;              // 32 lanes per box
    int pl = gid & 31;
    int b = box >> 11;
    float val = 0.f;
    if (pl < PDIM) {
        long bb = (long)box * 7;
        float xg = boxes[bb + 0], yg = boxes[bb + 1];
        float wg = boxes[bb + 3], lg = boxes[bb + 4];
        float rg = boxes[bb + 6];
        float ct = cosf(rg), st = sinf(rg);
        const float lxv[4] = {-0.5f, -0.16666667f, 0.16666667f, 0.5f};
        const float lyv[7] = {-0.5f, -0.33333334f, -0.16666667f, 0.f,
                               0.16666667f, 0.33333334f, 0.5f};
        int h = pl / 7, ww = pl - (pl / 7) * 7;
        float xx = lxv[h] * wg;
        float yy = lyv[ww] * lg;
        float gx = (xx * ct + yy * st + xg) * 2.5f;           // GRID_OFF.x = 0
        float gy = (yy * ct - xx * st + yg + 40.f) * 2.5f;    // GRID_OFF.y = 40
        float x0 = floorf(gx), y0 = floorf(gy);
        float fx = gx - x0, fy = gy - y0;
        int xi = (int)x0, yi = (int)y0;
        const float* base = feat2 + (long)b * HWDIM * PDIM + pl;
        float Ia = 0.f, Ib = 0.f, Ic = 0.f, Id = 0.f;
        if (yi >= 0 && yi < HDIM) {
            long r0 = (long)yi * WDIM;
            if (xi >= 0 && xi < WDIM)         Ia = base[(r0 + xi) * PDIM];
            if (xi + 1 >= 0 && xi + 1 < WDIM) Ic = base[(r0 + xi + 1) * PDIM];
        }
        if (yi + 1 >= 0 && yi + 1 < HDIM) {
            long r1 = (long)(yi + 1) * WDIM;
            if (xi >= 0 && xi < WDIM)         Ib = base[(r1 + xi) * PDIM];
            if (xi + 1 >= 0 && xi + 1 < WDIM) Id = base[(r1 + xi + 1) * PDIM];
        }
        val = (1.f - fx) * (1.f - fy) * Ia + (1.f - fx) * fy * Ib
            + fx * (1.f - fy) * Ic + fx * fy * Id;
    }
#pragma unroll
    for (int m = 16; m >= 1; m >>= 1) val += __shfl_xor(val, m, 64);
    if ((threadIdx.x & 31) == 0) {
        out[box] = val * (1.f / 28.f);
    }
}

// ---------- launch ----------
extern "C" void kernel_launch(void* const* d_in, const int* in_sizes, int n_in,
                              void* d_out, int out_size, void* d_ws, size_t ws_size,
                              hipStream_t stream) {
    const float* x     = (const float*)d_in[0];
    const float* boxes = (const float*)d_in[1];
    const float* w1    = (const float*)d_in[2];
    const float* g     = (const float*)d_in[3];
    const float* bt    = (const float*)d_in[4];
    const float* mn    = (const float*)d_in[5];
    const float* vr    = (const float*)d_in[6];
    const float* w2    = (const float*)d_in[7];
    float* out = (float*)d_out;

    char* ws = (char*)d_ws;
    unsigned short* xT2  = (unsigned short*)ws;                // 72,089,600 B
    float* feat2         = (float*)(ws + 72089600);            // 15,769,600 B
    unsigned short* BwT2 = (unsigned short*)(ws + 90112000);   //    147,456 B
    float* scale         = (float*)(ws + 90259456);            //        128 B
    float* shift         = (float*)(ws + 90259584);            //        128 B

    transpose_kernel<<<dim3(550, 4, 4), 256, 0, stream>>>(x, xT2);
    prep_kernel<<<289, 256, 0, stream>>>(w1, g, bt, mn, vr, BwT2, scale, shift);
    conv1_kernel<<<dim3(1200, 4), 64, 0, stream>>>(xT2, BwT2, scale, shift, w2, feat2);
    sample_kernel<<<1024, 256, 0, stream>>>(boxes, feat2, out);
}